// Round 19
// baseline (653.231 us; speedup 1.0000x reference)
//
#include <hip/hip_runtime.h>
#include <hip/hip_fp16.h>

using i32x4  = __attribute__((ext_vector_type(4)))  int;
using i32x16 = __attribute__((ext_vector_type(16))) int;

static constexpr int M  = 4 * 2048;   // 8192 rows (B*S)
static constexpr int N  = 4096;       // OUT_F
static constexpr int K  = 4096;       // IN_F
static constexpr int NT = K / 64;     // 64 K-tiles
static constexpr int ATILE = 256 * 64;  // 16 KB packed A tile (256-row)
static constexpr int BTILE = 128 * 64;  //  8 KB packed B tile (128-col)

// ---------------- fused pack kernel: int32 -> blocked int8 tiles -------------
// A tile (16 KB): [kg(4)][row(256)][16B]   wa: [M/256][NT][ATILE]
// B tile ( 8 KB): [kg(4)][col(128)][16B]   wb: [N/128][NT][BTILE] (transposed)
static constexpr int PX_BLOCKS = (int)((size_t)M * K / 16 / 256);  // 8192
static constexpr int PW_BLOCKS = (int)((size_t)N * K / 16 / 256);  // 4096

__device__ __forceinline__ unsigned pack4(i32x4 v) {
  return (unsigned)((v.x & 255) | ((v.y & 255) << 8) | ((v.z & 255) << 16) | (v.w << 24));
}

__global__ __launch_bounds__(256) void pack_kernel(const int* __restrict__ x,
                                                   const int* __restrict__ w,
                                                   unsigned char* __restrict__ wa,
                                                   unsigned char* __restrict__ wb) {
  if (blockIdx.x < PX_BLOCKS) {
    unsigned g = blockIdx.x * 256 + threadIdx.x;   // dest 16B granule, < M*K/16
    unsigned row = g & 255;
    unsigned kg  = (g >> 8) & 3;
    unsigned kt  = (g >> 10) & 63;
    unsigned br  = g >> 16;
    const int* src = x + ((size_t)(br * 256 + row) * K + kt * 64 + kg * 16);
    i32x4 v0 = *(const i32x4*)(src + 0);
    i32x4 v1 = *(const i32x4*)(src + 4);
    i32x4 v2 = *(const i32x4*)(src + 8);
    i32x4 v3 = *(const i32x4*)(src + 12);
    i32x4 d;
    d.x = (int)pack4(v0); d.y = (int)pack4(v1); d.z = (int)pack4(v2); d.w = (int)pack4(v3);
    *(i32x4*)(wa + (size_t)g * 16) = d;
  } else {
    unsigned g = (blockIdx.x - PX_BLOCKS) * 256 + threadIdx.x;  // < N*K/16
    unsigned col = g & 127;
    unsigned kg  = (g >> 7) & 3;
    unsigned kt  = (g >> 9) & 63;
    unsigned bn  = g >> 15;
    unsigned n   = bn * 128 + col;
    unsigned k0  = kt * 64 + kg * 16;
    const int* src = w + (size_t)k0 * N + n;
    i32x4 d;
#pragma unroll
    for (int j = 0; j < 4; ++j) {
      int b0 = src[(size_t)(j * 4 + 0) * N];
      int b1 = src[(size_t)(j * 4 + 1) * N];
      int b2 = src[(size_t)(j * 4 + 2) * N];
      int b3 = src[(size_t)(j * 4 + 3) * N];
      d[j] = (b0 & 255) | ((b1 & 255) << 8) | ((b2 & 255) << 16) | (b3 << 24);
    }
    *(i32x4*)(wb + (size_t)g * 16) = d;
  }
}

// -- GEMM: producer-consumer, 2 CONSUMERS PER SIMD. 256x256 block, 768 thr. --
// Waves 0-7: consumers (4x2 grid, wave tile 64x128, acc[2][4]) — ds_read A
//   (4/step, LDS sub-parity) + B direct L2->VGPR (parity dbuf) + MFMA.
//   2 consumers share each SIMD: one's LDS wait overlaps the other's MFMA.
// Waves 8-11: producers (1/SIMD) — gload_lds A into 3-slot ring, vmcnt(4).

__device__ __forceinline__ void gload_lds16(const void* g, void* l) {
  __builtin_amdgcn_global_load_lds((const __attribute__((address_space(1))) unsigned int*)g,
                                   (__attribute__((address_space(3))) unsigned int*)l,
                                   16, 0, 0);
}

#define FENCE()   asm volatile("" ::: "memory")
#define BARRIER() do { FENCE(); __builtin_amdgcn_s_barrier(); FENCE(); } while (0)

__global__ __launch_bounds__(768, 1) void gemm_i8(const unsigned char* __restrict__ wa,
                                                  const unsigned char* __restrict__ wb,
                                                  const __half* __restrict__ bias,
                                                  const float* __restrict__ alphaP,
                                                  float* __restrict__ out) {
  __shared__ __align__(16) unsigned char As[3][ATILE];   // 48 KB: 3-slot A ring

  const int tid  = threadIdx.x;
  const int lane = tid & 63;
  const int w    = tid >> 6;            // wave 0..11
  const int l31  = lane & 31;
  const int kgl  = lane >> 5;

  const int bc = blockIdx.x;            // 0..15 (N/256)
  const int br = blockIdx.y;            // 0..31 (M/256)

  const unsigned char* ga = wa + (size_t)br * NT * ATILE;   // 256-row A panel

  if (w >= 8) {
    // ------------------------- PRODUCER (1 per SIMD) -----------------------
    const int pw = w - 8;               // 0..3
    const int poff = pw * 4096;         // 4 KB segment of 16 KB tile

#define STAGE(T) do {                                                          \
      const unsigned char* src = ga + (size_t)(T) * ATILE + poff + lane * 16;  \
      unsigned char* dst = &As[(T) % 3][poff];                                 \
      gload_lds16(src +    0, dst +    0);                                     \
      gload_lds16(src + 1024, dst + 1024);                                     \
      gload_lds16(src + 2048, dst + 2048);                                     \
      gload_lds16(src + 3072, dst + 3072);                                     \
    } while (0)

    STAGE(0);
    STAGE(1);
    asm volatile("s_waitcnt vmcnt(4)" ::: "memory");   // slot 0 complete
    BARRIER();
    for (int t = 0; t < NT; ++t) {
      if (t + 2 < NT) STAGE(t + 2);                    // slot (t+2)%3 free
      if (t + 2 < NT)      asm volatile("s_waitcnt vmcnt(4)" ::: "memory");
      else if (t + 1 < NT) asm volatile("s_waitcnt vmcnt(0)" ::: "memory");
      BARRIER();                                       // slot t+1 resident
    }
#undef STAGE
    return;   // producers skip epilogue
  }

  // --------------------------- CONSUMER (2 per SIMD) -----------------------
  const int cr = w >> 1, cc = w & 1;    // 4 x 2 grid; wave tile 64 x 128
  const int arow = cr * 64 + l31;       // A frag row base
  const int bcl  = l31;                 // within-panel col base

  // this wave's 128-col B panel (2 panels per block, picked by cc)
  const unsigned char* gbw = wb + (size_t)(bc * 2 + cc) * NT * BTILE;

  i32x4 b[2][2][4];                     // [parity][kc][ni] — const indices
  i32x16 acc[2][4] = {};

#define BLOAD(PAR, T) do {                                                     \
    const unsigned char* bt = gbw + (size_t)(T) * BTILE;                       \
    b[PAR][0][0] = *(const i32x4*)(bt + (kgl)     * 2048 + (bcl +  0) * 16);   \
    b[PAR][0][1] = *(const i32x4*)(bt + (kgl)     * 2048 + (bcl + 32) * 16);   \
    b[PAR][0][2] = *(const i32x4*)(bt + (kgl)     * 2048 + (bcl + 64) * 16);   \
    b[PAR][0][3] = *(const i32x4*)(bt + (kgl)     * 2048 + (bcl + 96) * 16);   \
    b[PAR][1][0] = *(const i32x4*)(bt + (2 + kgl) * 2048 + (bcl +  0) * 16);   \
    b[PAR][1][1] = *(const i32x4*)(bt + (2 + kgl) * 2048 + (bcl + 32) * 16);   \
    b[PAR][1][2] = *(const i32x4*)(bt + (2 + kgl) * 2048 + (bcl + 64) * 16);   \
    b[PAR][1][3] = *(const i32x4*)(bt + (2 + kgl) * 2048 + (bcl + 96) * 16);   \
  } while (0)

#define CHUNK(SLOT, KC, PAR) do {                                              \
    const unsigned char* Ap = (SLOT) + ((KC) * 2 + kgl) * 4096;                \
    i32x4 a0 = *(const i32x4*)(Ap + (arow +  0) * 16);                         \
    i32x4 a1 = *(const i32x4*)(Ap + (arow + 32) * 16);                         \
    acc[0][0] = __builtin_amdgcn_mfma_i32_32x32x32_i8(a0, b[PAR][KC][0], acc[0][0], 0, 0, 0); \
    acc[0][1] = __builtin_amdgcn_mfma_i32_32x32x32_i8(a0, b[PAR][KC][1], acc[0][1], 0, 0, 0); \
    acc[0][2] = __builtin_amdgcn_mfma_i32_32x32x32_i8(a0, b[PAR][KC][2], acc[0][2], 0, 0, 0); \
    acc[0][3] = __builtin_amdgcn_mfma_i32_32x32x32_i8(a0, b[PAR][KC][3], acc[0][3], 0, 0, 0); \
    acc[1][0] = __builtin_amdgcn_mfma_i32_32x32x32_i8(a1, b[PAR][KC][0], acc[1][0], 0, 0, 0); \
    acc[1][1] = __builtin_amdgcn_mfma_i32_32x32x32_i8(a1, b[PAR][KC][1], acc[1][1], 0, 0, 0); \
    acc[1][2] = __builtin_amdgcn_mfma_i32_32x32x32_i8(a1, b[PAR][KC][2], acc[1][2], 0, 0, 0); \
    acc[1][3] = __builtin_amdgcn_mfma_i32_32x32x32_i8(a1, b[PAR][KC][3], acc[1][3], 0, 0, 0); \
  } while (0)

#define CSTEP(T, PAR) do {                                                     \
    if ((T) + 1 < NT) BLOAD(PAR ^ 1, (T) + 1);   /* next B, covered by MFMA */ \
    const unsigned char* slot = &As[(T) % 3][0];                               \
    __builtin_amdgcn_s_setprio(1);                                             \
    CHUNK(slot, 0, PAR);                                                       \
    CHUNK(slot, 1, PAR);                                                       \
    __builtin_amdgcn_s_setprio(0);                                             \
    BARRIER();                                                                 \
  } while (0)

  BLOAD(0, 0);
  BARRIER();                            // matches producer prologue barrier
  for (int t = 0; t < NT; t += 2) {     // NT = 64, even
    CSTEP(t, 0);
    CSTEP(t + 1, 1);
  }

  // epilogue: C/D layout col=lane&31, row=(r&3)+8*(r>>2)+4*(lane>>5)
  const float alpha = *alphaP;
  const int row0 = br * 256 + cr * 64 + 4 * kgl;
  const int col0 = bc * 256 + cc * 128 + l31;
#pragma unroll
  for (int ni = 0; ni < 4; ++ni) {
    const int col = col0 + ni * 32;
    const float bf = __half2float(bias[col]);
#pragma unroll
    for (int mi = 0; mi < 2; ++mi) {
#pragma unroll
      for (int r = 0; r < 16; ++r) {
        const int row = row0 + mi * 32 + (r & 3) + 8 * (r >> 2);
        out[(size_t)row * N + col] = ((float)acc[mi][ni][r] + bf) * alpha;
      }
    }
  }
#undef CSTEP
#undef CHUNK
#undef BLOAD
}

extern "C" void kernel_launch(void* const* d_in, const int* in_sizes, int n_in,
                              void* d_out, int out_size, void* d_ws, size_t ws_size,
                              hipStream_t stream) {
  const int*    x     = (const int*)d_in[0];
  const int*    wgt   = (const int*)d_in[1];
  const __half* bias  = (const __half*)d_in[2];
  const float*  alpha = (const float*)d_in[3];
  float*        out   = (float*)d_out;

  // workspace: packed A (32 MB) + packed B (16 MB) = 48 MB
  unsigned char* wa = (unsigned char*)d_ws;
  unsigned char* wb = wa + (size_t)M * K;

  pack_kernel<<<PX_BLOCKS + PW_BLOCKS, 256, 0, stream>>>(x, wgt, wa, wb);

  dim3 grid(N / 256, M / 256);   // 16 x 32 = 512 blocks
  gemm_i8<<<grid, 768, 0, stream>>>(wa, wb, bias, alpha, out);
}

// Round 20
// 244.476 us; speedup vs baseline: 2.6720x; 2.6720x over previous
//
#include <hip/hip_runtime.h>
#include <hip/hip_fp16.h>

using i32x4  = __attribute__((ext_vector_type(4)))  int;
using i32x16 = __attribute__((ext_vector_type(16))) int;

static constexpr int M  = 4 * 2048;   // 8192 rows (B*S)
static constexpr int N  = 4096;       // OUT_F
static constexpr int K  = 4096;       // IN_F
static constexpr int NT = K / 64;     // 64 K-tiles
static constexpr int ATILE = 256 * 64;  // 16 KB packed A tile (256-row)
static constexpr int BTILE = 128 * 64;  //  8 KB packed B tile (128-col)

// ---------------- fused pack kernel: int32 -> blocked int8 tiles -------------
// A tile (16 KB): [kg(4)][row(256)][16B]   wa: [M/256][NT][ATILE]
// B tile ( 8 KB): [kg(4)][col(128)][16B]   wb: [N/128][NT][BTILE] (transposed)
static constexpr int PX_BLOCKS = (int)((size_t)M * K / 16 / 256);  // 8192
static constexpr int PW_BLOCKS = (int)((size_t)N * K / 16 / 256);  // 4096

__device__ __forceinline__ unsigned pack4(i32x4 v) {
  return (unsigned)((v.x & 255) | ((v.y & 255) << 8) | ((v.z & 255) << 16) | (v.w << 24));
}

__global__ __launch_bounds__(256) void pack_kernel(const int* __restrict__ x,
                                                   const int* __restrict__ w,
                                                   unsigned char* __restrict__ wa,
                                                   unsigned char* __restrict__ wb) {
  if (blockIdx.x < PX_BLOCKS) {
    unsigned g = blockIdx.x * 256 + threadIdx.x;   // dest 16B granule, < M*K/16
    unsigned row = g & 255;
    unsigned kg  = (g >> 8) & 3;
    unsigned kt  = (g >> 10) & 63;
    unsigned br  = g >> 16;
    const int* src = x + ((size_t)(br * 256 + row) * K + kt * 64 + kg * 16);
    i32x4 v0 = *(const i32x4*)(src + 0);
    i32x4 v1 = *(const i32x4*)(src + 4);
    i32x4 v2 = *(const i32x4*)(src + 8);
    i32x4 v3 = *(const i32x4*)(src + 12);
    i32x4 d;
    d.x = (int)pack4(v0); d.y = (int)pack4(v1); d.z = (int)pack4(v2); d.w = (int)pack4(v3);
    *(i32x4*)(wa + (size_t)g * 16) = d;
  } else {
    unsigned g = (blockIdx.x - PX_BLOCKS) * 256 + threadIdx.x;  // < N*K/16
    unsigned col = g & 127;
    unsigned kg  = (g >> 7) & 3;
    unsigned kt  = (g >> 9) & 63;
    unsigned bn  = g >> 15;
    unsigned n   = bn * 128 + col;
    unsigned k0  = kt * 64 + kg * 16;
    const int* src = w + (size_t)k0 * N + n;
    i32x4 d;
#pragma unroll
    for (int j = 0; j < 4; ++j) {
      int b0 = src[(size_t)(j * 4 + 0) * N];
      int b1 = src[(size_t)(j * 4 + 1) * N];
      int b2 = src[(size_t)(j * 4 + 2) * N];
      int b3 = src[(size_t)(j * 4 + 3) * N];
      d[j] = (b0 & 255) | ((b1 & 255) << 8) | ((b2 & 255) << 16) | (b3 << 24);
    }
    *(i32x4*)(wb + (size_t)g * 16) = d;
  }
}

// -- GEMM: producer-consumer, 2 consumers + 1 producer per SIMD, REG-SIZED. ---
// Block 256x128, 768 threads. Waves 0-7: consumers (4x2 grid, wave tile 64x64,
//   acc[2][2]=64 AGPR + 32 B-VGPR ~ 130 regs < 170 budget at 3 waves/SIMD).
// Waves 8-11: producers — gload_lds A (16 KB/tile) into 3-slot ring, vmcnt(4).
// B direct L2->VGPR, parity dbuf. One barrier per K-tile.

__device__ __forceinline__ void gload_lds16(const void* g, void* l) {
  __builtin_amdgcn_global_load_lds((const __attribute__((address_space(1))) unsigned int*)g,
                                   (__attribute__((address_space(3))) unsigned int*)l,
                                   16, 0, 0);
}

#define FENCE()   asm volatile("" ::: "memory")
#define BARRIER() do { FENCE(); __builtin_amdgcn_s_barrier(); FENCE(); } while (0)

__global__ __launch_bounds__(768, 3) void gemm_i8(const unsigned char* __restrict__ wa,
                                                  const unsigned char* __restrict__ wb,
                                                  const __half* __restrict__ bias,
                                                  const float* __restrict__ alphaP,
                                                  float* __restrict__ out) {
  __shared__ __align__(16) unsigned char As[3][ATILE];   // 48 KB: 3-slot A ring

  const int tid  = threadIdx.x;
  const int lane = tid & 63;
  const int w    = tid >> 6;            // wave 0..11 (w%4 = SIMD id)
  const int l31  = lane & 31;
  const int kgl  = lane >> 5;

  const int bc = blockIdx.x;            // 0..31 (N/128)
  const int br = blockIdx.y;            // 0..31 (M/256)

  const unsigned char* ga = wa + (size_t)br * NT * ATILE;   // 256-row A panel

  if (w >= 8) {
    // ------------------------- PRODUCER (1 per SIMD) -----------------------
    const int pw = w - 8;               // 0..3
    const int poff = pw * 4096;         // 4 KB segment of 16 KB tile

#define STAGE(T) do {                                                          \
      const unsigned char* src = ga + (size_t)(T) * ATILE + poff + lane * 16;  \
      unsigned char* dst = &As[(T) % 3][poff];                                 \
      gload_lds16(src +    0, dst +    0);                                     \
      gload_lds16(src + 1024, dst + 1024);                                     \
      gload_lds16(src + 2048, dst + 2048);                                     \
      gload_lds16(src + 3072, dst + 3072);                                     \
    } while (0)

    STAGE(0);
    STAGE(1);
    asm volatile("s_waitcnt vmcnt(4)" ::: "memory");   // slot 0 complete
    BARRIER();
    for (int t = 0; t < NT; ++t) {
      if (t + 2 < NT) STAGE(t + 2);                    // slot (t+2)%3 free
      if (t + 2 < NT)      asm volatile("s_waitcnt vmcnt(4)" ::: "memory");
      else if (t + 1 < NT) asm volatile("s_waitcnt vmcnt(0)" ::: "memory");
      BARRIER();                                       // slot t+1 resident
    }
#undef STAGE
    return;   // producers skip epilogue
  }

  // ---------------------- CONSUMER (2 per SIMD) ----------------------------
  const int cr = w >> 1, cc = w & 1;    // 4 x 2 grid; wave tile 64 x 64
  const int arow = cr * 64 + l31;       // A frag row base
  const int bcol = cc * 64 + l31;       // B frag col base (within 128-panel)

  const unsigned char* gbw = wb + (size_t)bc * NT * BTILE;  // 128-col B panel

  i32x4 b[2][2][2];                     // [parity][kc][ni] — const indices
  i32x16 acc[2][2] = {};

#define BLOAD(PAR, T) do {                                                     \
    const unsigned char* bt = gbw + (size_t)(T) * BTILE;                       \
    b[PAR][0][0] = *(const i32x4*)(bt + (kgl)     * 2048 + (bcol +  0) * 16);  \
    b[PAR][0][1] = *(const i32x4*)(bt + (kgl)     * 2048 + (bcol + 32) * 16);  \
    b[PAR][1][0] = *(const i32x4*)(bt + (2 + kgl) * 2048 + (bcol +  0) * 16);  \
    b[PAR][1][1] = *(const i32x4*)(bt + (2 + kgl) * 2048 + (bcol + 32) * 16);  \
  } while (0)

#define CHUNK(SLOT, KC, PAR) do {                                              \
    const unsigned char* Ap = (SLOT) + ((KC) * 2 + kgl) * 4096;                \
    i32x4 a0 = *(const i32x4*)(Ap + (arow +  0) * 16);                         \
    i32x4 a1 = *(const i32x4*)(Ap + (arow + 32) * 16);                         \
    acc[0][0] = __builtin_amdgcn_mfma_i32_32x32x32_i8(a0, b[PAR][KC][0], acc[0][0], 0, 0, 0); \
    acc[0][1] = __builtin_amdgcn_mfma_i32_32x32x32_i8(a0, b[PAR][KC][1], acc[0][1], 0, 0, 0); \
    acc[1][0] = __builtin_amdgcn_mfma_i32_32x32x32_i8(a1, b[PAR][KC][0], acc[1][0], 0, 0, 0); \
    acc[1][1] = __builtin_amdgcn_mfma_i32_32x32x32_i8(a1, b[PAR][KC][1], acc[1][1], 0, 0, 0); \
  } while (0)

#define CSTEP(T, PAR) do {                                                     \
    if ((T) + 1 < NT) BLOAD(PAR ^ 1, (T) + 1);   /* next B, covered by MFMA */ \
    const unsigned char* slot = &As[(T) % 3][0];                               \
    __builtin_amdgcn_s_setprio(1);                                             \
    CHUNK(slot, 0, PAR);                                                       \
    CHUNK(slot, 1, PAR);                                                       \
    __builtin_amdgcn_s_setprio(0);                                             \
    BARRIER();                                                                 \
  } while (0)

  BLOAD(0, 0);
  BARRIER();                            // matches producer prologue barrier
  for (int t = 0; t < NT; t += 2) {     // NT = 64, even
    CSTEP(t, 0);
    CSTEP(t + 1, 1);
  }

  // epilogue: C/D layout col=lane&31, row=(r&3)+8*(r>>2)+4*(lane>>5)
  const float alpha = *alphaP;
  const int row0 = br * 256 + cr * 64 + 4 * kgl;
  const int col0 = bc * 128 + cc * 64 + l31;
#pragma unroll
  for (int ni = 0; ni < 2; ++ni) {
    const int col = col0 + ni * 32;
    const float bf = __half2float(bias[col]);
#pragma unroll
    for (int mi = 0; mi < 2; ++mi) {
#pragma unroll
      for (int r = 0; r < 16; ++r) {
        const int row = row0 + mi * 32 + (r & 3) + 8 * (r >> 2);
        out[(size_t)row * N + col] = ((float)acc[mi][ni][r] + bf) * alpha;
      }
    }
  }
#undef CSTEP
#undef CHUNK
#undef BLOAD
}

extern "C" void kernel_launch(void* const* d_in, const int* in_sizes, int n_in,
                              void* d_out, int out_size, void* d_ws, size_t ws_size,
                              hipStream_t stream) {
  const int*    x     = (const int*)d_in[0];
  const int*    wgt   = (const int*)d_in[1];
  const __half* bias  = (const __half*)d_in[2];
  const float*  alpha = (const float*)d_in[3];
  float*        out   = (float*)d_out;

  // workspace: packed A (32 MB) + packed B (16 MB) = 48 MB
  unsigned char* wa = (unsigned char*)d_ws;
  unsigned char* wb = wa + (size_t)M * K;

  pack_kernel<<<PX_BLOCKS + PW_BLOCKS, 256, 0, stream>>>(x, wgt, wa, wb);

  dim3 grid(N / 128, M / 256);   // 32 x 32 = 1024 blocks
  gemm_i8<<<grid, 768, 0, stream>>>(wa, wb, bias, alpha, out);
}

// Round 21
// 224.952 us; speedup vs baseline: 2.9039x; 1.0868x over previous
//
#include <hip/hip_runtime.h>
#include <hip/hip_fp16.h>

using i32x4  = __attribute__((ext_vector_type(4)))  int;
using i32x16 = __attribute__((ext_vector_type(16))) int;

static constexpr int M  = 4 * 2048;   // 8192 rows (B*S)
static constexpr int N  = 4096;       // OUT_F
static constexpr int K  = 4096;       // IN_F
static constexpr int NT = K / 64;     // 64 K-tiles
static constexpr int NS = K / 256;    // 16 slots (4 K-tiles each)
static constexpr int ATILE = 256 * 64;  // 16 KB packed A tile (256-row)
static constexpr int BTILE = 128 * 64;  //  8 KB packed B tile (128-col)

// ---------------- fused pack kernel: int32 -> blocked int8 tiles -------------
// A tile (16 KB): [kg(4)][row(256)][16B]   wa: [M/256][NT][ATILE]
// B tile ( 8 KB): [kg(4)][col(128)][16B]   wb: [N/128][NT][BTILE] (transposed)
static constexpr int PX_BLOCKS = (int)((size_t)M * K / 16 / 256);  // 8192
static constexpr int PW_BLOCKS = (int)((size_t)N * K / 16 / 256);  // 4096

__device__ __forceinline__ unsigned pack4(i32x4 v) {
  return (unsigned)((v.x & 255) | ((v.y & 255) << 8) | ((v.z & 255) << 16) | (v.w << 24));
}

__global__ __launch_bounds__(256) void pack_kernel(const int* __restrict__ x,
                                                   const int* __restrict__ w,
                                                   unsigned char* __restrict__ wa,
                                                   unsigned char* __restrict__ wb) {
  if (blockIdx.x < PX_BLOCKS) {
    unsigned g = blockIdx.x * 256 + threadIdx.x;   // dest 16B granule, < M*K/16
    unsigned row = g & 255;
    unsigned kg  = (g >> 8) & 3;
    unsigned kt  = (g >> 10) & 63;
    unsigned br  = g >> 16;
    const int* src = x + ((size_t)(br * 256 + row) * K + kt * 64 + kg * 16);
    i32x4 v0 = *(const i32x4*)(src + 0);
    i32x4 v1 = *(const i32x4*)(src + 4);
    i32x4 v2 = *(const i32x4*)(src + 8);
    i32x4 v3 = *(const i32x4*)(src + 12);
    i32x4 d;
    d.x = (int)pack4(v0); d.y = (int)pack4(v1); d.z = (int)pack4(v2); d.w = (int)pack4(v3);
    *(i32x4*)(wa + (size_t)g * 16) = d;
  } else {
    unsigned g = (blockIdx.x - PX_BLOCKS) * 256 + threadIdx.x;  // < N*K/16
    unsigned col = g & 127;
    unsigned kg  = (g >> 7) & 3;
    unsigned kt  = (g >> 9) & 63;
    unsigned bn  = g >> 15;
    unsigned n   = bn * 128 + col;
    unsigned k0  = kt * 64 + kg * 16;
    const int* src = w + (size_t)k0 * N + n;
    i32x4 d;
#pragma unroll
    for (int j = 0; j < 4; ++j) {
      int b0 = src[(size_t)(j * 4 + 0) * N];
      int b1 = src[(size_t)(j * 4 + 1) * N];
      int b2 = src[(size_t)(j * 4 + 2) * N];
      int b3 = src[(size_t)(j * 4 + 3) * N];
      d[j] = (b0 & 255) | ((b1 & 255) << 8) | ((b2 & 255) << 16) | (b3 << 24);
    }
    *(i32x4*)(wb + (size_t)g * 16) = d;
  }
}

// -- GEMM: producer-consumer, QUAD-TILE SLOTS (BK=256), 2-slot ring, 128 KB. --
// Block 256x128, 512 threads. Waves 0-3: consumers (2x2 grid, wave tile
//   128x64, acc[4][2]) — 64 MFMAs per slot-step (4684 cyc/SIMD of cover).
// Waves 4-7: producers — 16 outstanding gload_lds each (64 KB/CU in flight),
//   staging ~1400 cyc << consumer step. ONE barrier per slot (16 total).
// B direct L2->VGPR, parity dbuf per K-tile, covered by a full tile of MFMA.

__device__ __forceinline__ void gload_lds16(const void* g, void* l) {
  __builtin_amdgcn_global_load_lds((const __attribute__((address_space(1))) unsigned int*)g,
                                   (__attribute__((address_space(3))) unsigned int*)l,
                                   16, 0, 0);
}

#define FENCE()   asm volatile("" ::: "memory")
#define BARRIER() do { FENCE(); __builtin_amdgcn_s_barrier(); FENCE(); } while (0)

__global__ __launch_bounds__(512, 1) void gemm_i8(const unsigned char* __restrict__ wa,
                                                  const unsigned char* __restrict__ wb,
                                                  const __half* __restrict__ bias,
                                                  const float* __restrict__ alphaP,
                                                  float* __restrict__ out) {
  __shared__ __align__(16) unsigned char As[2][65536];   // 128 KB: 2 slots x 4 A-tiles

  const int tid  = threadIdx.x;
  const int lane = tid & 63;
  const int w    = tid >> 6;            // wave 0..7
  const int cw   = w & 3;
  const int l31  = lane & 31;
  const int kgl  = lane >> 5;

  const int bc = blockIdx.x;            // 0..31 (N/128)
  const int br = blockIdx.y;            // 0..31 (M/256)

  const unsigned char* ga = wa + (size_t)br * NT * ATILE;   // 256-row A panel

  if (w >= 4) {
    // ------------------------- PRODUCER (1 per SIMD) -----------------------
    const int poff = cw * 16384;        // this wave's 16 KB of the 64 KB slot

#define STAGE(S) do {                                                          \
      const unsigned char* src = ga + (size_t)(S) * 65536 + poff + lane * 16;  \
      unsigned char* dst = &As[(S) & 1][poff];                                 \
      _Pragma("unroll")                                                        \
      for (int j = 0; j < 16; ++j)                                             \
        gload_lds16(src + j * 1024, dst + j * 1024);                           \
    } while (0)

    STAGE(0);
    asm volatile("s_waitcnt vmcnt(0)" ::: "memory");
    BARRIER();                           // slot 0 ready
    for (int s = 0; s < NS; ++s) {
      if (s + 1 < NS) {
        STAGE(s + 1);                    // slot (s+1)&1 was freed at barrier s-1
        asm volatile("s_waitcnt vmcnt(0)" ::: "memory");
      }
      BARRIER();                         // end of step s: slot s+1 resident
    }
#undef STAGE
    return;   // producers skip epilogue
  }

  // --------------------------- CONSUMER (1 per SIMD) -----------------------
  const int cr = cw >> 1, cc = cw & 1;  // 2 x 2 grid; wave tile 128 x 64
  const int arow = cr * 128 + l31;      // A frag row base
  const int bcol = cc * 64 + l31;       // B frag col base (within 128-panel)

  const unsigned char* gbw = wb + (size_t)bc * NT * BTILE;  // 128-col B panel

  i32x4 b[2][2][2];                     // [parity][kc][ni] — const indices
  i32x16 acc[4][2] = {};

#define BLOAD(PAR, T) do {                                                     \
    const unsigned char* bt = gbw + (size_t)(T) * BTILE;                       \
    b[PAR][0][0] = *(const i32x4*)(bt + (kgl)     * 2048 + (bcol +  0) * 16);  \
    b[PAR][0][1] = *(const i32x4*)(bt + (kgl)     * 2048 + (bcol + 32) * 16);  \
    b[PAR][1][0] = *(const i32x4*)(bt + (2 + kgl) * 2048 + (bcol +  0) * 16);  \
    b[PAR][1][1] = *(const i32x4*)(bt + (2 + kgl) * 2048 + (bcol + 32) * 16);  \
  } while (0)

#define CHUNK(TOFF, KC, PAR) do {                                              \
    const unsigned char* Ap = slot + (TOFF) + ((KC) * 2 + kgl) * 4096;         \
    i32x4 a0 = *(const i32x4*)(Ap + (arow +  0) * 16);                         \
    i32x4 a1 = *(const i32x4*)(Ap + (arow + 32) * 16);                         \
    i32x4 a2 = *(const i32x4*)(Ap + (arow + 64) * 16);                         \
    i32x4 a3 = *(const i32x4*)(Ap + (arow + 96) * 16);                         \
    acc[0][0] = __builtin_amdgcn_mfma_i32_32x32x32_i8(a0, b[PAR][KC][0], acc[0][0], 0, 0, 0); \
    acc[0][1] = __builtin_amdgcn_mfma_i32_32x32x32_i8(a0, b[PAR][KC][1], acc[0][1], 0, 0, 0); \
    acc[1][0] = __builtin_amdgcn_mfma_i32_32x32x32_i8(a1, b[PAR][KC][0], acc[1][0], 0, 0, 0); \
    acc[1][1] = __builtin_amdgcn_mfma_i32_32x32x32_i8(a1, b[PAR][KC][1], acc[1][1], 0, 0, 0); \
    acc[2][0] = __builtin_amdgcn_mfma_i32_32x32x32_i8(a2, b[PAR][KC][0], acc[2][0], 0, 0, 0); \
    acc[2][1] = __builtin_amdgcn_mfma_i32_32x32x32_i8(a2, b[PAR][KC][1], acc[2][1], 0, 0, 0); \
    acc[3][0] = __builtin_amdgcn_mfma_i32_32x32x32_i8(a3, b[PAR][KC][0], acc[3][0], 0, 0, 0); \
    acc[3][1] = __builtin_amdgcn_mfma_i32_32x32x32_i8(a3, b[PAR][KC][1], acc[3][1], 0, 0, 0); \
  } while (0)

  // per K-tile j within the slot (par = j&1, compile-time after unroll):
  // prefetch B(tt+1) into par^1, then 2 chunks (16 MFMAs) on tile j.
#define TILE_J(S, J) do {                                                      \
    const int tt = (S) * 4 + (J);                                              \
    if (tt + 1 < NT) BLOAD(((J) + 1) & 1, tt + 1);                             \
    __builtin_amdgcn_s_setprio(1);                                             \
    CHUNK((J) * 16384, 0, (J) & 1);                                            \
    CHUNK((J) * 16384, 1, (J) & 1);                                            \
    __builtin_amdgcn_s_setprio(0);                                             \
  } while (0)

  BLOAD(0, 0);
  BARRIER();                            // matches producer prologue barrier
  for (int s = 0; s < NS; ++s) {        // 16 slot-steps
    const unsigned char* slot = &As[s & 1][0];
    TILE_J(s, 0);
    TILE_J(s, 1);
    TILE_J(s, 2);
    TILE_J(s, 3);
    BARRIER();                          // slot s free; slot s+1 resident
  }

  // epilogue: C/D layout col=lane&31, row=(r&3)+8*(r>>2)+4*(lane>>5)
  const float alpha = *alphaP;
  const int row0 = br * 256 + cr * 128 + 4 * kgl;
  const int col0 = bc * 128 + cc * 64 + l31;
#pragma unroll
  for (int ni = 0; ni < 2; ++ni) {
    const int col = col0 + ni * 32;
    const float bf = __half2float(bias[col]);
#pragma unroll
    for (int mi = 0; mi < 4; ++mi) {
#pragma unroll
      for (int r = 0; r < 16; ++r) {
        const int row = row0 + mi * 32 + (r & 3) + 8 * (r >> 2);
        out[(size_t)row * N + col] = ((float)acc[mi][ni][r] + bf) * alpha;
      }
    }
  }
#undef TILE_J
#undef CHUNK
#undef BLOAD
}

extern "C" void kernel_launch(void* const* d_in, const int* in_sizes, int n_in,
                              void* d_out, int out_size, void* d_ws, size_t ws_size,
                              hipStream_t stream) {
  const int*    x     = (const int*)d_in[0];
  const int*    wgt   = (const int*)d_in[1];
  const __half* bias  = (const __half*)d_in[2];
  const float*  alpha = (const float*)d_in[3];
  float*        out   = (float*)d_out;

  // workspace: packed A (32 MB) + packed B (16 MB) = 48 MB
  unsigned char* wa = (unsigned char*)d_ws;
  unsigned char* wb = wa + (size_t)M * K;

  pack_kernel<<<PX_BLOCKS + PW_BLOCKS, 256, 0, stream>>>(x, wgt, wa, wb);

  dim3 grid(N / 128, M / 256);   // 32 x 32 = 1024 blocks
  gemm_i8<<<grid, 512, 0, stream>>>(wa, wb, bias, alpha, out);
}